// Round 3
// baseline (967.044 us; speedup 1.0000x reference)
//
#include <hip/hip_runtime.h>

// VectorQuantizer: x (4,256,16,32,32) f32, weight (1024,256) f32.
// out[n*256+c] = weight[argmin_k d(n,k)][c], n in BTHW token order.
//
// Round 3: bit-replicate the numpy fp32 reference. Evidence: R1 (fp32
// approx) and R2 (fp64 exact) produced IDENTICAL absmax 1.934e-3 -> ref
// resolves ~300 near-tie tokens on its own fp32 grid (ulp(256)~3e-5) with
// np.argmin first-index ties. So we reproduce numpy's exact arithmetic:
//   sx[n]  = np pairwise-sum(x_n^2)   (8-chain tree, halves of 128)
//   sw[k]  = np pairwise-sum(w_k^2)   (same tree)
//   m[n,k] = sgemm dot: single sequential fma chain over c ascending
//   d      = fp32(fp32(sx+sw) - 2*m)  (2*m exact; fmaf(-2,m,s) == np rounding)
//   argmin = first index of minimum.

#define TPB 32       // tokens per block
#define THREADS 256

// ---- numpy pairwise sum of squares, n=256, contract OFF (mul then add) ----
__device__ __forceinline__ float np_sumsq_256(const float* __restrict__ p,
                                              long stride) {
#pragma clang fp contract(off)
    float half[2];
    #pragma unroll
    for (int h = 0; h < 2; ++h) {
        const float* q = p + (long)h * 128 * stride;
        float r[8];
        #pragma unroll
        for (int j = 0; j < 8; ++j) { float v = q[(long)j * stride]; r[j] = v * v; }
        for (int i = 8; i < 128; i += 8) {
            #pragma unroll
            for (int j = 0; j < 8; ++j) {
                float v = q[(long)(i + j) * stride];
                r[j] = r[j] + v * v;
            }
        }
        half[h] = ((r[0] + r[1]) + (r[2] + r[3])) + ((r[4] + r[5]) + (r[6] + r[7]));
    }
    return half[0] + half[1];
}

// ---- prep: sx per token (reads coalesced across threads) ----
__global__ __launch_bounds__(256) void vq_sxq(const float* __restrict__ x,
                                              float* __restrict__ sxq) {
    const int n = blockIdx.x * 256 + threadIdx.x;   // 0..65535
    const int b = n >> 14, thw = n & 16383;
    sxq[n] = np_sumsq_256(x + (long)b * 4194304 + thw, 16384);
}

// ---- prep: sw per code ----
__global__ __launch_bounds__(256) void vq_swq(const float* __restrict__ w,
                                              float* __restrict__ swq) {
    const int k = blockIdx.x * 256 + threadIdx.x;   // 0..1023
    swq[k] = np_sumsq_256(w + (long)k * 256, 1);
}

// ---- prep: W transpose Wt[c][k] ----
__global__ __launch_bounds__(64) void vq_wt(const float* __restrict__ w,
                                            float* __restrict__ wt) {
    const int k = blockIdx.x;      // 0..1023
    const int lane = threadIdx.x;  // 0..63
    const float4 v = reinterpret_cast<const float4*>(w + (size_t)k * 256)[lane];
    wt[(size_t)(4 * lane + 0) * 1024 + k] = v.x;
    wt[(size_t)(4 * lane + 1) * 1024 + k] = v.y;
    wt[(size_t)(4 * lane + 2) * 1024 + k] = v.z;
    wt[(size_t)(4 * lane + 3) * 1024 + k] = v.w;
}

// ---- main: sequential-fma dots + np-exact distance + first-index argmin ----
__global__ __launch_bounds__(THREADS) void vq_main(const float* __restrict__ weight,
                                                   const float* __restrict__ x,
                                                   const float* __restrict__ sxq,
                                                   const float* __restrict__ swq,
                                                   const float* __restrict__ wt,
                                                   float* __restrict__ out) {
    __shared__ __align__(16) float xs[256 * TPB];   // [c][t], 32 KB
    __shared__ float wn[1024];                      // sw, 4 KB
    __shared__ float sxs[TPB];
    __shared__ float red_s[4][TPB];
    __shared__ int   red_i[4][TPB];
    __shared__ int   fidx[TPB];

    const int tid = threadIdx.x;
    const int n0 = blockIdx.x * TPB;
    const int b   = n0 >> 14;
    const int thw = n0 & 16383;
    const float* xb = x + (size_t)b * 4194304 + thw;

    for (int i = tid; i < 256 * TPB; i += THREADS) {
        int t = i & (TPB - 1);
        int c = i >> 5;
        xs[c * TPB + t] = xb[(size_t)c * 16384 + t];
    }
    for (int i = tid; i < 1024; i += THREADS) wn[i] = swq[i];
    if (tid < TPB) sxs[tid] = sxq[n0 + tid];
    __syncthreads();

    const int lane = tid & 63;
    const int wv   = tid >> 6;    // wave 0..3
    const int tg   = lane & 7;    // tokens 4*tg .. 4*tg+3
    const int cg   = lane >> 3;   // code subgroup 0..7

    float sxr[4];
    #pragma unroll
    for (int j = 0; j < 4; j++) sxr[j] = sxs[4 * tg + j];

    float bestS[4];
    int   bestI[4];
    #pragma unroll
    for (int j = 0; j < 4; j++) { bestS[j] = 1e30f; bestI[j] = 0x7fffffff; }

    for (int kb = 0; kb < 1024; kb += 256) {
        const int kbase = kb + 64 * wv + 8 * cg;  // this thread's 8 codes
        float acc[4][8];
        #pragma unroll
        for (int j = 0; j < 4; j++)
            #pragma unroll
            for (int q = 0; q < 8; q++) acc[j][q] = 0.f;

        const float* wtp = wt + kbase;
        // sequential fma chain over c ascending == BLAS sgemm per-element order
        #pragma unroll 4
        for (int c = 0; c < 256; c++) {
            const float4 xv = *reinterpret_cast<const float4*>(
                &xs[c * TPB + 4 * tg]);
            const float4 w0 = *reinterpret_cast<const float4*>(wtp + (size_t)c * 1024);
            const float4 w1 = *reinterpret_cast<const float4*>(wtp + (size_t)c * 1024 + 4);
            const float xr[4] = {xv.x, xv.y, xv.z, xv.w};
            const float wr[8] = {w0.x, w0.y, w0.z, w0.w, w1.x, w1.y, w1.z, w1.w};
            #pragma unroll
            for (int j = 0; j < 4; j++)
                #pragma unroll
                for (int q = 0; q < 8; q++)
                    acc[j][q] = fmaf(xr[j], wr[q], acc[j][q]);
        }
        // d = fp32(fp32(sx+sw) - 2*m); running first-index argmin (k ascending)
        #pragma unroll
        for (int q = 0; q < 8; q++) {
            const int k = kbase + q;
            const float wnk = wn[k];
            #pragma unroll
            for (int j = 0; j < 4; j++) {
                const float s1 = sxr[j] + wnk;              // np: sum_x + sum_w (rounded)
                const float d  = fmaf(-2.f, acc[j][q], s1); // np: s1 - 2*m (one rounding)
                if (d < bestS[j]) { bestS[j] = d; bestI[j] = k; }
            }
        }
    }

    // merge across lanes sharing tg (XOR 8,16,32): lexicographic (score, index)
    #pragma unroll
    for (int m = 8; m < 64; m <<= 1) {
        #pragma unroll
        for (int j = 0; j < 4; j++) {
            const float os = __shfl_xor(bestS[j], m);
            const int   oi = __shfl_xor(bestI[j], m);
            if (os < bestS[j] || (os == bestS[j] && oi < bestI[j])) {
                bestS[j] = os; bestI[j] = oi;
            }
        }
    }
    if (cg == 0) {
        #pragma unroll
        for (int j = 0; j < 4; j++) {
            red_s[wv][4 * tg + j] = bestS[j];
            red_i[wv][4 * tg + j] = bestI[j];
        }
    }
    __syncthreads();
    if (tid < TPB) {
        float bs = red_s[0][tid];
        int   bi = red_i[0][tid];
        #pragma unroll
        for (int w2 = 1; w2 < 4; w2++) {
            const float s2 = red_s[w2][tid];
            const int   i2 = red_i[w2][tid];
            if (s2 < bs || (s2 == bs && i2 < bi)) { bs = s2; bi = i2; }
        }
        fidx[tid] = bi;
    }
    __syncthreads();

    // gather: out[(n0+t)*256 + c] = weight[fidx[t]*256 + c], coalesced over c
    for (int i = tid; i < TPB * 256; i += THREADS) {
        const int t = i >> 8;
        const int c = i & 255;
        out[(size_t)(n0 + t) * 256 + c] = weight[(size_t)fidx[t] * 256 + c];
    }
}

extern "C" void kernel_launch(void* const* d_in, const int* in_sizes, int n_in,
                              void* d_out, int out_size, void* d_ws, size_t ws_size,
                              hipStream_t stream) {
    const float* x = (const float*)d_in[0];   // 16777216 floats
    const float* w = (const float*)d_in[1];   // 262144 floats
    float* out = (float*)d_out;

    float* sxq = (float*)d_ws;                // 65536
    float* swq = sxq + 65536;                 // 1024
    float* wt  = swq + 1024;                  // 262144  (Wt[256][1024])

    vq_sxq<<<256, 256, 0, stream>>>(x, sxq);
    vq_swq<<<4, 256, 0, stream>>>(w, swq);
    vq_wt<<<1024, 64, 0, stream>>>(w, wt);
    vq_main<<<65536 / TPB, THREADS, 0, stream>>>(w, x, sxq, swq, wt, out);
}